// Round 7
// baseline (217.147 us; speedup 1.0000x reference)
//
#include <hip/hip_runtime.h>
#include <math.h>

// Problem constants (B=2, N=1024, DE=1024, H=16, DH=64 complex dims/head)
#define BB      2
#define NN      1024
#define DE_     1024
#define HH      16
#define TWO_DK  2048
#define PK      4194304     // B*H*N*128 packed elements per q/k/v stream
#define TBLR    1092        // per-head table entries: dt in [-64, 1028)

typedef float f32x4  __attribute__((ext_vector_type(4)));
typedef short bf16x8 __attribute__((ext_vector_type(8)));

__device__ __forceinline__ short f2bf(float f) {
    unsigned u = __float_as_uint(f);
    unsigned r = (u + 0x7fffu + ((u >> 16) & 1u)) >> 16;   // RNE
    return (short)r;
}
__device__ __forceinline__ float bf2f(short v) {
    return __uint_as_float(((unsigned)(unsigned short)v) << 16);
}

// raw v_exp_f32 / v_log_f32 (both base-2 on AMD HW). HIP lacks __exp2f/__log2f.
__device__ __forceinline__ float fexp2(float x) { return __builtin_amdgcn_exp2f(x); }
__device__ __forceinline__ float flog2(float x) { return __builtin_amdgcn_logf(x); }

#define GLDS16(g, l) __builtin_amdgcn_global_load_lds(                        \
    (const __attribute__((address_space(1))) unsigned int*)(g),               \
    (__attribute__((address_space(3))) unsigned int*)(l), 16, 0, 0)
#define GLDS4(g, l) __builtin_amdgcn_global_load_lds(                         \
    (const __attribute__((address_space(1))) unsigned int*)(g),               \
    (__attribute__((address_space(3))) unsigned int*)(l), 4, 0, 0)

// ---------------------------------------------------------------------------
// R17 attention job lists: grid 512 = exact resident-slot count. Per bh, 16
// blocks with total load EXACTLY 8 (grp 0..7) or 9 (grp 8..15) KV-tiles:
//   g0..g7 : first halves (jt 0..7) of it 15..9 + it15 second half -- psel 1/2
//   g8     : it8 whole (9 tiles, direct)
//   g9..15 : second halves of it 14..9 paired with singles it 1..6; g9 = it7+it0
// Co-resident pair (rest, rest+32) -> (grp, grp+8) -> CU load 17 uniformly.
// ANY pairing still gives 16-18 -> bounded downside. Splits of it 9..15 at
// j=8; part1 never touches diagonal. Job1 (if any) is always a direct single.
// ---------------------------------------------------------------------------
__constant__ signed char gIT0[16] = {15,15,14,13,12,11,10, 9, 8, 7,14,13,12,11,10, 9};
__constant__ signed char gJ00[16] = { 0, 8, 0, 0, 0, 0, 0, 0, 0, 0, 8, 8, 8, 8, 8, 8};
__constant__ signed char gJ10[16] = { 7,15, 7, 7, 7, 7, 7, 7, 8, 7,14,13,12,11,10, 9};
__constant__ signed char gPS0[16] = { 1, 2, 1, 1, 1, 1, 1, 1, 0, 0, 2, 2, 2, 2, 2, 2};
__constant__ signed char gIT1[16] = {-1,-1,-1,-1,-1,-1,-1,-1,-1, 0, 1, 2, 3, 4, 5, 6};

// ---------------------------------------------------------------------------
// prep: z=0..2 transpose Wq/Wk/Wv -> wt[n][k] bf16; z=3,bx<16 transpose Wo;
//       z=3,bx>=16 decay tables; z=4 x fp32->bf16.
// Table entries: x = 2*E, y = 1/V, z = -32*log2(V), w = E*E (log2 units).
// ---------------------------------------------------------------------------
__global__ __launch_bounds__(256) void prep(
    const float* __restrict__ x,
    const float* __restrict__ Wq, const float* __restrict__ Wk,
    const float* __restrict__ Wv, const float* __restrict__ Wo,
    const float* __restrict__ mu_raw, const float* __restrict__ sigma_raw,
    const float* __restrict__ eta_raw, const float* __restrict__ gamma_raw,
    short* __restrict__ xb, short* __restrict__ wt, short* __restrict__ wot,
    float4* __restrict__ tbl) {
    const int z = blockIdx.z;
    if (z == 4) {
        const int flat = blockIdx.y * 32 + blockIdx.x;
        const int i = (flat * 256 + threadIdx.x) * 8;
        float4 v0 = *(const float4*)&x[i];
        float4 v1 = *(const float4*)&x[i + 4];
        short4 o0, o1;
        o0.x = f2bf(v0.x); o0.y = f2bf(v0.y); o0.z = f2bf(v0.z); o0.w = f2bf(v0.w);
        o1.x = f2bf(v1.x); o1.y = f2bf(v1.y); o1.z = f2bf(v1.z); o1.w = f2bf(v1.w);
        *(short4*)&xb[i] = o0; *(short4*)&xb[i + 4] = o1;
        return;
    }
    if (z == 3 && blockIdx.x >= 16) {
        const int idx = blockIdx.y * 16 + (blockIdx.x - 16);
        if (idx >= 80) return;
        const int h = idx / 5, rb = idx % 5;
        const int r = rb * 256 + threadIdx.x;
        if (r >= TBLR) return;
        const float mu = 1.f / (1.f + expf(-mu_raw[h])) + 1e-4f;
        const float Ac = log1pf(expf(sigma_raw[h])) / (2.f * mu);
        const float Cc = log1pf(expf(eta_raw[h])) + log1pf(expf(gamma_raw[h]));
        const float arg = fminf(fmaxf(-mu * (float)(r - 64), -30.f), 0.f);
        const float E   = expf(arg);
        const float V   = fmaf(Ac, 1.f - E * E, Cc);
        tbl[h * TBLR + r] = make_float4(2.f * E, 1.f / V, -32.f * log2f(V), E * E);
        return;
    }
    const float* in; short* out; int R, C;
    if (z < 3) { if (blockIdx.y >= 16) return;
                 in = (z == 0) ? Wq : (z == 1) ? Wk : Wv;
                 out = wt + (size_t)z * 2097152; R = 1024; C = 2048; }
    else       { in = Wo; out = wot; R = 2048; C = 1024; }
    __shared__ float t[64][65];
    const int c0 = blockIdx.x * 64, r0 = blockIdx.y * 64;
    const int tr = threadIdx.x >> 4, tc4 = (threadIdx.x & 15) * 4;
#pragma unroll
    for (int s = 0; s < 4; ++s) {
        const int r = tr + s * 16;
        float4 v = *(const float4*)&in[(size_t)(r0 + r) * C + c0 + tc4];
        t[r][tc4] = v.x; t[r][tc4 + 1] = v.y; t[r][tc4 + 2] = v.z; t[r][tc4 + 3] = v.w;
    }
    __syncthreads();
#pragma unroll
    for (int s = 0; s < 4; ++s) {
        const int oc = tr + s * 16;
        short4 o;
        o.x = f2bf(t[tc4 + 0][oc]); o.y = f2bf(t[tc4 + 1][oc]);
        o.z = f2bf(t[tc4 + 2][oc]); o.w = f2bf(t[tc4 + 3][oc]);
        *(short4*)&out[(size_t)(c0 + oc) * R + r0 + tc4] = o;
    }
}

// ---------------------------------------------------------------------------
// QKV GEMM + fused RoPE rotation/norms. R17: B-operand DIRECT global->reg
// (wave-private 32 rows -- no cross-wave reuse, so LDS staging of B only
// burned LDS ports: per-iter LDS read 48->32KB, write 24->8KB, and the
// barrier now protects just 2 A-loads). Swizzle algebra collapses to
// bf[b] = W[wrow(wc+b*16+fr)][k0+ks+quad*8], plain 16B loads, 4/lane/iter,
// same L2 traffic. 64x128 tile, grid (32,16,3), LDS 9.2KB, (256,4).
// ---------------------------------------------------------------------------
__global__ __launch_bounds__(256, 4) void gemm_qkv_rot2(
    const short* __restrict__ A, const short* __restrict__ wt,
    const float* __restrict__ omega,
    short* __restrict__ qb, short* __restrict__ kb, short* __restrict__ vtb,
    float* __restrict__ qn_, float* __restrict__ kn_) {
    __shared__ __align__(16) short As[64 * 64];
    __shared__ float sN[4][64];
    const int tid = threadIdx.x;
    const int m0  = blockIdx.x * 64;
    const int h   = blockIdx.y;
    const short* W = wt + (size_t)blockIdx.z * 2097152;

    const short* aP[2]; int aOff[2];
#pragma unroll
    for (int i = 0; i < 2; ++i) {
        const int c   = i * 256 + tid;
        const int row = c >> 3;
        const int src = ((c & 7) ^ (row & 7)) << 3;
        aOff[i] = c * 8;
        aP[i] = A + (size_t)(m0 + row) * 1024 + src;
    }

    const int lane = tid & 63, w = tid >> 6;
    const int wc = w * 32;
    const int fr = lane & 15, quad = lane >> 4;
    const int fo = quad << 3;
    const int sw = (fr & 7) << 3;

    // B fragment rows -> W rows (dcol remap folded in)
    const int rB0 = wc + fr, rB1 = wc + 16 + fr;
    const short* wB0 = W + (size_t)(((rB0 >> 4) & 1) * 1024 + h * 64 +
                                    (rB0 >> 5) * 16 + (rB0 & 15)) * 1024 + fo;
    const short* wB1 = W + (size_t)(((rB1 >> 4) & 1) * 1024 + h * 64 +
                                    (rB1 >> 5) * 16 + (rB1 & 15)) * 1024 + fo;

    f32x4 acc[4][2];
#pragma unroll
    for (int a = 0; a < 4; ++a)
#pragma unroll
        for (int b = 0; b < 2; ++b) acc[a][b] = (f32x4){0.f, 0.f, 0.f, 0.f};

    for (int k0 = 0; k0 < 1024; k0 += 64) {
#pragma unroll
        for (int i = 0; i < 2; ++i) GLDS16(aP[i] + k0, &As[aOff[i]]);
        bf16x8 b00 = *(const bf16x8*)(wB0 + k0);
        bf16x8 b01 = *(const bf16x8*)(wB0 + k0 + 32);
        bf16x8 b10 = *(const bf16x8*)(wB1 + k0);
        bf16x8 b11 = *(const bf16x8*)(wB1 + k0 + 32);
        __syncthreads();
        bf16x8 af0[4], af1[4];
#pragma unroll
        for (int a = 0; a < 4; ++a)
            af0[a] = *(const bf16x8*)&As[(a * 16 + fr) * 64 + (fo ^ sw)];
#pragma unroll
        for (int a = 0; a < 4; ++a)
            af1[a] = *(const bf16x8*)&As[(a * 16 + fr) * 64 + ((32 + fo) ^ sw)];
#pragma unroll
        for (int a = 0; a < 4; ++a) {
            acc[a][0] = __builtin_amdgcn_mfma_f32_16x16x32_bf16(af0[a], b00, acc[a][0], 0, 0, 0);
            acc[a][1] = __builtin_amdgcn_mfma_f32_16x16x32_bf16(af0[a], b10, acc[a][1], 0, 0, 0);
        }
#pragma unroll
        for (int a = 0; a < 4; ++a) {
            acc[a][0] = __builtin_amdgcn_mfma_f32_16x16x32_bf16(af1[a], b01, acc[a][0], 0, 0, 0);
            acc[a][1] = __builtin_amdgcn_mfma_f32_16x16x32_bf16(af1[a], b11, acc[a][1], 0, 0, 0);
        }
        __syncthreads();
    }

    const int cq = quad * 4, l15 = lane & 15;
    const int bh  = (m0 >> 10) * 16 + h;
    const int nb0 = (m0 & 1023) + cq;

    if (blockIdx.z == 2) {
#pragma unroll
        for (int a = 0; a < 4; ++a) {
#pragma unroll
            for (int b = 0; b < 2; ++b) {
                const int cl = wc + b * 16;
                const int dd = ((cl >> 4) & 1) * 64 + (cl >> 5) * 16 + l15;
                short4 o;
                o.x = f2bf(acc[a][b][0]); o.y = f2bf(acc[a][b][1]);
                o.z = f2bf(acc[a][b][2]); o.w = f2bf(acc[a][b][3]);
                *(short4*)&vtb[((size_t)bh * 128 + dd) * 1024 + nb0 + a * 16] = o;
            }
        }
        return;
    }
    float* nout = (blockIdx.z == 0) ? qn_ : kn_;
    short* obuf = (blockIdx.z == 0) ? qb  : kb;

#pragma unroll
    for (int a = 0; a < 4; ++a) {
        float ns[4] = {0.f, 0.f, 0.f, 0.f};
#pragma unroll
        for (int b = 0; b < 2; ++b)
#pragma unroll
            for (int r = 0; r < 4; ++r)
                ns[r] = fmaf(acc[a][b][r], acc[a][b][r], ns[r]);
#pragma unroll
        for (int m2 = 1; m2 < 16; m2 <<= 1)
#pragma unroll
            for (int r = 0; r < 4; ++r) ns[r] += __shfl_xor(ns[r], m2);
        if (l15 == 0)
#pragma unroll
            for (int r = 0; r < 4; ++r) sN[w][a * 16 + cq + r] = ns[r];
    }
    __syncthreads();
    if (tid < 64)
        nout[(size_t)bh * 1024 + (m0 & 1023) + tid] =
            sN[0][tid] + sN[1][tid] + sN[2][tid] + sN[3][tid];

    {
        const int d = w * 16 + l15;            // complex dim 0..63
        const float om = (d < 32) ? omega[h * 32 + d] : -omega[h * 32 + d - 32];
#pragma unroll
        for (int a = 0; a < 4; ++a) {
#pragma unroll
            for (int r = 0; r < 4; ++r) {
                const int n2 = nb0 + a * 16 + r;
                float sn, cs;
                __sincosf((float)n2 * om, &sn, &cs);
                const float re = acc[a][0][r], im = acc[a][1][r];
                short* orow = obuf + ((size_t)bh * 1024 + n2) * 128;
                orow[d]      = f2bf(re * cs - im * sn);
                orow[64 + d] = f2bf(re * sn + im * cs);
            }
        }
    }
}

// ---------------------------------------------------------------------------
// MFMA flash attention (R17): per-block job LISTS (see tables above). 512
// blocks, each runs 1-2 jobs totaling exactly 8-9 KV tiles; every CU gets
// 16-18 tiles regardless of pairing. Split tiles (it 9..15) emit normalized
// partials + LSE; attn_merge (224 tiles) combines. Softmax diet: MFMA
// ones-column row-sums, exp2/log2 rebase, table folds, defer-max THR=16.
// LDS: Ks 32K + Vs 32K + Ps 9216 + sT 4096 + sKn 512 = 79360 -> 2 blocks/CU.
// ---------------------------------------------------------------------------
__global__ __launch_bounds__(256) void attn_mfma(
    const short* __restrict__ qr, const short* __restrict__ kr,
    const short* __restrict__ vt,
    const float* __restrict__ qn, const float* __restrict__ kn,
    const float4* __restrict__ tbl,
    const float* __restrict__ tau_p, const float* __restrict__ nu_raw,
    short* __restrict__ y, short* __restrict__ po0, float* __restrict__ pml) {
    __shared__ __align__(16) short Ks[2][64 * 128];
    __shared__ __align__(16) short Vs[2][128 * 64];
    __shared__ __align__(16) short Ps[64 * 72];
    __shared__ __align__(16) float4 sT[2][128];
    __shared__ float sKn[2][64];

    const int bx   = blockIdx.x;
    const int xcd  = bx & 7;
    const int rest = bx >> 3;                 // 0..63
    const int bh   = xcd * 4 + (rest & 3);    // 4 bh per XCD (L2 locality)
    const int grp  = rest >> 2;               // 0..15 job-list index
    const int h    = bh & 15;

    const int tid  = threadIdx.x;
    const int lane = tid & 63, w = tid >> 6;
    const int quad = lane >> 4, l15 = lane & 15;

    const float nu     = log1pf(expf(nu_raw[h]));
    const float coef   = -0.5f * tau_p[h] * (nu + 64.0f);
    const float inv_nu = 1.f / nu;

    const short* Qb  = qr + (size_t)bh * NN * 128;
    const short* Kb  = kr + (size_t)bh * NN * 128;
    const short* Vtb = vt + (size_t)bh * 128 * NN;

    const bf16x8 onesv = (bf16x8){0x3F80, 0x3F80, 0x3F80, 0x3F80,
                                  0x3F80, 0x3F80, 0x3F80, 0x3F80};
    const bool has2 = (gIT1[grp] >= 0);

#define STAGE(JT, P) do {                                                     \
        const int j0_ = (JT) * 64, dt0_ = i0 - j0_;                           \
        _Pragma("unroll")                                                     \
        for (int i_ = 0; i_ < 4; ++i_) {                                      \
            const int c_ = i_ * 256 + tid, row_ = c_ >> 4;                    \
            const int src_ = ((c_ & 15) ^ (row_ & 7)) * 8;                    \
            GLDS16(Kb + (size_t)(j0_ + row_) * 128 + src_, &Ks[P][c_ * 8]);   \
        }                                                                     \
        _Pragma("unroll")                                                     \
        for (int i_ = 0; i_ < 4; ++i_) {                                      \
            const int c_ = i_ * 256 + tid, d_ = c_ >> 3;                      \
            const int src_ = ((c_ & 7) ^ (d_ & 7)) * 8;                       \
            GLDS16(Vtb + (size_t)d_ * NN + j0_ + src_, &Vs[P][c_ * 8]);       \
        }                                                                     \
        if (w == 0) {                                                         \
            GLDS16(tbl + h * TBLR + 1 + dt0_ + lane, &sT[P][lane]);           \
            GLDS16(tbl + h * TBLR + 65 + dt0_ + lane, &sT[P][64 + lane]);     \
        } else if (w == 1) {                                                  \
            GLDS4(kn + (size_t)bh * NN + j0_ + lane, &sKn[P][lane]);          \
        }                                                                     \
    } while (0)

    for (int jj = 0; jj < 2; ++jj) {
        int it, j0j, j1j, psel;
        if (jj == 0) {
            it = gIT0[grp]; j0j = gJ00[grp]; j1j = gJ10[grp]; psel = gPS0[grp];
        } else {
            if (!has2) break;
            it = gIT1[grp]; j0j = 0; j1j = it; psel = 0;
        }
        const int i0 = it * 64;
        const int pq = bh * 7 + (it - 9);     // partial slot (psel != 0 only)

        bf16x8 qf[4];
        const int arow = i0 + w * 16 + l15;
#pragma unroll
        for (int ks = 0; ks < 4; ++ks)
            qf[ks] = *(const bf16x8*)&Qb[(size_t)arow * 128 + ks * 32 + quad * 8];

        float mrow[4];
        f32x4 o[8];
        f32x4 o9 = (f32x4){0.f, 0.f, 0.f, 0.f};  // row-sums via ones-column
#pragma unroll
        for (int r = 0; r < 4; ++r) mrow[r] = -INFINITY;
#pragma unroll
        for (int s = 0; s < 8; ++s) o[s] = (f32x4){0.f, 0.f, 0.f, 0.f};
        float qn4[4];
#pragma unroll
        for (int r = 0; r < 4; ++r)
            qn4[r] = qn[(size_t)bh * NN + i0 + w * 16 + quad * 4 + r];

        STAGE(j0j, 0);
        __syncthreads();

        for (int jt = j0j; jt <= j1j; ++jt) {
            const int p = (jt - j0j) & 1;
            if (jt < j1j) STAGE(jt + 1, 1 - p);  // async prefetch; drained at barrier

            f32x4 sAcc[4];
#pragma unroll
            for (int s = 0; s < 4; ++s) sAcc[s] = (f32x4){0.f, 0.f, 0.f, 0.f};
#pragma unroll
            for (int ks = 0; ks < 4; ++ks) {
#pragma unroll
                for (int s = 0; s < 4; ++s) {
                    const int brow = s * 16 + l15;
                    bf16x8 bK = *(const bf16x8*)&Ks[p][brow * 128 +
                                                      (((ks * 4 + quad) ^ (brow & 7)) * 8)];
                    sAcc[s] = __builtin_amdgcn_mfma_f32_16x16x32_bf16(qf[ks], bK, sAcc[s], 0, 0, 0);
                }
            }

            float al[4];
            bool anyr = false;
#pragma unroll
            for (int r = 0; r < 4; ++r) {
                const int row = w * 16 + quad * 4 + r;
                float lg[4];
#pragma unroll
                for (int s = 0; s < 4; ++s) {
                    const int col = s * 16 + l15;
                    const float4 T = sT[p][row - col + 63];
                    const float sv = sAcc[s][r];
                    const float t1 = fmaf(T.w, sKn[p][col], qn4[r]);     // qn + E^2*kn
                    const float maha = fmaxf(fmaf(-T.x, sv, t1), 0.f) * T.y;
                    float v = fmaf(coef, flog2(fmaf(maha, inv_nu, 1.f)), T.z);
                    if (jt == it && col > row) v = -INFINITY;
                    lg[s] = v;
                }
                float mx = fmaxf(fmaxf(lg[0], lg[1]), fmaxf(lg[2], lg[3]));
                mx = fmaxf(mx, __shfl_xor(mx, 1));
                mx = fmaxf(mx, __shfl_xor(mx, 2));
                mx = fmaxf(mx, __shfl_xor(mx, 4));
                mx = fmaxf(mx, __shfl_xor(mx, 8));
                const bool resc = mx > mrow[r] + 16.f;   // defer-max
                const float mu_ = resc ? mx : mrow[r];
                al[r] = resc ? fexp2(mrow[r] - mx) : 1.f;
                mrow[r] = mu_;
                anyr = anyr || resc;
#pragma unroll
                for (int s = 0; s < 4; ++s) {
                    const float pv = fexp2(lg[s] - mu_);
                    Ps[row * 72 + s * 16 + l15] = f2bf(pv);
                }
            }
            if (anyr) {
#pragma unroll
                for (int s = 0; s < 8; ++s)
#pragma unroll
                    for (int r = 0; r < 4; ++r) o[s][r] *= al[r];
#pragma unroll
                for (int r = 0; r < 4; ++r) o9[r] *= al[r];
            }

#pragma unroll
            for (int jc = 0; jc < 2; ++jc) {
                bf16x8 aP = *(const bf16x8*)&Ps[(w * 16 + l15) * 72 + jc * 32 + quad * 8];
#pragma unroll
                for (int sub = 0; sub < 8; ++sub) {
                    const int d = sub * 16 + l15;
                    bf16x8 bV = *(const bf16x8*)&Vs[p][d * 64 + (((jc * 4 + quad) ^ (d & 7)) * 8)];
                    o[sub] = __builtin_amdgcn_mfma_f32_16x16x32_bf16(aP, bV, o[sub], 0, 0, 0);
                }
                o9 = __builtin_amdgcn_mfma_f32_16x16x32_bf16(aP, onesv, o9, 0, 0, 0);
            }
            if (jt < j1j) __syncthreads();
        }

        // Epilogue: direct -> y; split -> normalized partial (o/l) + LSE.
        short* dst = (psel == 1) ? po0 : y;
        const size_t rbase = (psel == 1) ? (size_t)pq * 64 : ((size_t)bh * NN + i0);
#pragma unroll
        for (int r = 0; r < 4; ++r) {
            const int lrow = w * 16 + quad * 4 + r;
            const float inv = 1.f / o9[r];
            const size_t base = (rbase + lrow) * 128;
#pragma unroll
            for (int sub = 0; sub < 8; ++sub)
                dst[base + sub * 16 + l15] = f2bf(o[sub][r] * inv);
            if (psel != 0 && l15 == 0)
                pml[(pq * 2 + (psel - 1)) * 64 + lrow] = mrow[r] + flog2(o9[r]);
        }
        if (jj == 0 && has2) __syncthreads();   // protect LDS before job1 restages
    }
#undef STAGE
}

// ---------------------------------------------------------------------------
// LSE merge of split q-tiles (it 9..15 per bh): y = (o1n*w1 + o2n*w2)/(w1+w2).
// 224 blocks x 256 threads; in-place on y.
// ---------------------------------------------------------------------------
__global__ __launch_bounds__(256) void attn_merge(
    const short* __restrict__ po0, const float* __restrict__ pml,
    short* __restrict__ y) {
    const int qs = blockIdx.x;                // 0..223: bh*7 + (it-9)
    const int bh = qs / 7, it = qs % 7 + 9;
    const int t = threadIdx.x;
    const int row = t >> 2, dc = (t & 3) * 32;
    const float m1 = pml[(qs * 2 + 0) * 64 + row];
    const float m2 = pml[(qs * 2 + 1) * 64 + row];
    const float mx = fmaxf(m1, m2);
    const float w1 = fexp2(m1 - mx), w2 = fexp2(m2 - mx);
    const float inv = 1.f / (w1 + w2);
    const float a = w1 * inv, b = w2 * inv;
    const short* s1 = po0 + ((size_t)qs * 64 + row) * 128 + dc;
    short*       s2 = y + ((size_t)bh * NN + it * 64 + row) * 128 + dc;
#pragma unroll
    for (int i = 0; i < 32; i += 8) {
        bf16x8 v1 = *(const bf16x8*)(s1 + i);
        bf16x8 v2 = *(const bf16x8*)(s2 + i);
        bf16x8 ov;
#pragma unroll
        for (int k = 0; k < 8; ++k)
            ov[k] = f2bf(a * bf2f(v1[k]) + b * bf2f(v2[k]));
        *(bf16x8*)(s2 + i) = ov;
    }
}

// ---------------------------------------------------------------------------
// Output GEMM: out[2048][1024] = y @ Wo. 64x64 tiles, grid (32,16) = 512
// blocks, BK=64, direct f32 stores, 2-phase double-buffer. LDS 32KB.
// ---------------------------------------------------------------------------
__global__ __launch_bounds__(256) void gemm_out64(
    const short* __restrict__ yb, const short* __restrict__ wot,
    float* __restrict__ out) {
    __shared__ __align__(16) short As[2][64 * 64];
    __shared__ __align__(16) short Bs[2][64 * 64];
    const int tid = threadIdx.x;
    const int m0  = blockIdx.x * 64;
    const int n0  = blockIdx.y * 64;
    const int bb  = m0 >> 10;

    int aPre[2], aOff[2]; const short* bP[2];
#pragma unroll
    for (int i = 0; i < 2; ++i) {
        const int c = i * 256 + tid, row = c >> 3;
        const int src = ((c & 7) ^ (row & 7)) << 3;
        aPre[i] = ((m0 & 1023) + row) * 128 + src;
        bP[i] = wot + (size_t)(n0 + row) * 2048 + src;
        aOff[i] = c * 8;
    }

    const int lane = tid & 63, w = tid >> 6;
    const int wr = (w >> 1) * 32, wc = (w & 1) * 32;
    const int fr = lane & 15;
    const int fo = (lane >> 4) << 3;
    const int sw = (fr & 7) << 3;

    f32x4 acc[2][2];
#pragma unroll
    for (int a = 0; a < 2; ++a)
#pragma unroll
        for (int b = 0; b < 2; ++b) acc[a][b] = (f32x4){0.f, 0.f, 0.f, 0.f};

#define OSTAGE(KT, P) do {                                                    \
        const int k0_ = (KT) * 64;                                            \
        const int hh_ = (k0_ >> 6) & 15, im_ = k0_ >> 10;                     \
        const short* ab_ = yb + ((size_t)(bb * 16 + hh_) << 17) + im_ * 64;   \
        _Pragma("unroll")                                                     \
        for (int i_ = 0; i_ < 2; ++i_) GLDS16(ab_ + aPre[i_], &As[P][aOff[i_]]); \
        _Pragma("unroll")                                                     \
        for (int i_ = 0; i_ < 2; ++i_) GLDS16(bP[i_] + k0_, &Bs[P][aOff[i_]]);   \
    } while (0)

    OSTAGE(0, 0);
    __syncthreads();

    for (int kt = 0; kt < 32; ++kt) {
        const int p = kt & 1;
        if (kt < 31) OSTAGE(kt + 1, 1 - p);
#pragma unroll
        for (int ks = 0; ks < 64; ks += 32) {
            bf16x8 af[2], bf[2];
#pragma unroll
            for (int a = 0; a < 2; ++a)
                af[a] = *(const bf16x8*)&As[p][(wr + a * 16 + fr) * 64 + ((ks + fo) ^ sw)];
#pragma unroll
            for (int b = 0; b < 2; ++b)
                bf[b] = *(const bf16x8*)&Bs[p][(wc + b * 16 + fr) * 64 + ((ks + fo) ^ sw)];
#pragma unroll
            for (int a = 0; a < 2; ++a)
#pragma unroll
                for (int b = 0; b < 2; ++b)
                    acc[a][b] = __builtin_amdgcn_mfma_f32_16x16x32_bf16(
                        af[a], bf[b], acc[a][b], 0, 0, 0);
        }
        if (kt < 31) __syncthreads();
    }
#undef OSTAGE

    const int cq = (lane >> 4) * 4, l15 = lane & 15;
#pragma unroll
    for (int a = 0; a < 2; ++a)
#pragma unroll
        for (int b = 0; b < 2; ++b)
#pragma unroll
            for (int r = 0; r < 4; ++r)
                out[(size_t)(m0 + wr + a * 16 + cq + r) * 1024 +
                    (n0 + wc + b * 16 + l15)] = acc[a][b][r];
}

// ---------------------------------------------------------------------------
extern "C" void kernel_launch(void* const* d_in, const int* in_sizes, int n_in,
                              void* d_out, int out_size, void* d_ws, size_t ws_size,
                              hipStream_t stream) {
    const float* x         = (const float*)d_in[0];
    const float* Wq        = (const float*)d_in[1];
    const float* Wk        = (const float*)d_in[2];
    const float* Wv        = (const float*)d_in[3];
    const float* Wo        = (const float*)d_in[4];
    const float* omega     = (const float*)d_in[5];
    const float* mu_raw    = (const float*)d_in[6];
    const float* sigma_raw = (const float*)d_in[7];
    const float* eta_raw   = (const float*)d_in[8];
    const float* gamma_raw = (const float*)d_in[9];
    const float* tau       = (const float*)d_in[10];
    const float* nu_raw    = (const float*)d_in[11];
    float* out = (float*)d_out;

    short*  qb  = (short*)d_ws;
    short*  kb  = qb + PK;
    short*  vtb = kb + PK;
    float*  qn  = (float*)(vtb + PK);
    float*  kn  = qn + 32768;
    float4* tbl = (float4*)(kn + 32768);
    short*  wot = (short*)(tbl + HH * TBLR);
    short*  wt  = wot + 2097152;
    short*  xb  = wt + 3 * 2097152;
    short*  yb  = wt;                       // alias (wt dead after qkv)
    short*  po0 = wt + 4194304;             // first-half partials (wt tail)
    float*  pml = (float*)xb;               // per-row LSE partials (xb dead after qkv)

    prep<<<dim3(32, 32, 5), 256, 0, stream>>>(
        x, Wq, Wk, Wv, Wo, mu_raw, sigma_raw, eta_raw, gamma_raw,
        xb, wt, wot, tbl);
    gemm_qkv_rot2<<<dim3(32, 16, 3), 256, 0, stream>>>(
        xb, wt, omega, qb, kb, vtb, qn, kn);
    attn_mfma<<<dim3(512), 256, 0, stream>>>(
        qb, kb, vtb, qn, kn, tbl, tau, nu_raw, yb, po0, pml);
    attn_merge<<<dim3(224), 256, 0, stream>>>(po0, pml, yb);
    gemm_out64<<<dim3(32, 16), 256, 0, stream>>>(yb, wot, out);
}

// Round 8
// 201.239 us; speedup vs baseline: 1.0790x; 1.0790x over previous
//
#include <hip/hip_runtime.h>
#include <math.h>

// Problem constants (B=2, N=1024, DE=1024, H=16, DH=64 complex dims/head)
#define BB      2
#define NN      1024
#define DE_     1024
#define HH      16
#define TWO_DK  2048
#define PK      4194304     // B*H*N*128 packed elements per q/k/v stream
#define TBLR    1092        // per-head table entries: dt in [-64, 1028)

typedef float f32x4  __attribute__((ext_vector_type(4)));
typedef short bf16x8 __attribute__((ext_vector_type(8)));

__device__ __forceinline__ short f2bf(float f) {
    unsigned u = __float_as_uint(f);
    unsigned r = (u + 0x7fffu + ((u >> 16) & 1u)) >> 16;   // RNE
    return (short)r;
}
__device__ __forceinline__ float bf2f(short v) {
    return __uint_as_float(((unsigned)(unsigned short)v) << 16);
}

// raw v_exp_f32 / v_log_f32 (both base-2 on AMD HW). HIP lacks __exp2f/__log2f.
__device__ __forceinline__ float fexp2(float x) { return __builtin_amdgcn_exp2f(x); }
__device__ __forceinline__ float flog2(float x) { return __builtin_amdgcn_logf(x); }

#define GLDS16(g, l) __builtin_amdgcn_global_load_lds(                        \
    (const __attribute__((address_space(1))) unsigned int*)(g),               \
    (__attribute__((address_space(3))) unsigned int*)(l), 16, 0, 0)
#define GLDS4(g, l) __builtin_amdgcn_global_load_lds(                         \
    (const __attribute__((address_space(1))) unsigned int*)(g),               \
    (__attribute__((address_space(3))) unsigned int*)(l), 4, 0, 0)

// ---------------------------------------------------------------------------
// R17 attention job lists: grid 512 = exact resident-slot count. Per bh, 16
// blocks with total load EXACTLY 8 (grp 0..7) or 9 (grp 8..15) KV-tiles:
//   g0..g7 : first halves (jt 0..7) of it 15..9 + it15 second half -- psel 1/2
//   g8     : it8 whole (9 tiles, direct)
//   g9..15 : second halves of it 14..9 paired with singles it 1..6; g9 = it7+it0
// Co-resident pair (rest, rest+32) -> (grp, grp+8) -> CU load 17 uniformly.
// ANY pairing still gives 16-18 -> bounded downside. Splits of it 9..15 at
// j=8; part1 never touches diagonal. Job1 (if any) is always a direct single.
// ---------------------------------------------------------------------------
__constant__ signed char gIT0[16] = {15,15,14,13,12,11,10, 9, 8, 7,14,13,12,11,10, 9};
__constant__ signed char gJ00[16] = { 0, 8, 0, 0, 0, 0, 0, 0, 0, 0, 8, 8, 8, 8, 8, 8};
__constant__ signed char gJ10[16] = { 7,15, 7, 7, 7, 7, 7, 7, 8, 7,14,13,12,11,10, 9};
__constant__ signed char gPS0[16] = { 1, 2, 1, 1, 1, 1, 1, 1, 0, 0, 2, 2, 2, 2, 2, 2};
__constant__ signed char gIT1[16] = {-1,-1,-1,-1,-1,-1,-1,-1,-1, 0, 1, 2, 3, 4, 5, 6};

// ---------------------------------------------------------------------------
// prep: z=0..2 transpose Wq/Wk/Wv -> wt[n][k] bf16; z=3,bx<16 transpose Wo;
//       z=3,bx>=16 decay tables; z=4 x fp32->bf16.
// Table entries: x = 2*E, y = 1/V, z = -32*log2(V), w = E*E (log2 units).
// ---------------------------------------------------------------------------
__global__ __launch_bounds__(256) void prep(
    const float* __restrict__ x,
    const float* __restrict__ Wq, const float* __restrict__ Wk,
    const float* __restrict__ Wv, const float* __restrict__ Wo,
    const float* __restrict__ mu_raw, const float* __restrict__ sigma_raw,
    const float* __restrict__ eta_raw, const float* __restrict__ gamma_raw,
    short* __restrict__ xb, short* __restrict__ wt, short* __restrict__ wot,
    float4* __restrict__ tbl) {
    const int z = blockIdx.z;
    if (z == 4) {
        const int flat = blockIdx.y * 32 + blockIdx.x;
        const int i = (flat * 256 + threadIdx.x) * 8;
        float4 v0 = *(const float4*)&x[i];
        float4 v1 = *(const float4*)&x[i + 4];
        short4 o0, o1;
        o0.x = f2bf(v0.x); o0.y = f2bf(v0.y); o0.z = f2bf(v0.z); o0.w = f2bf(v0.w);
        o1.x = f2bf(v1.x); o1.y = f2bf(v1.y); o1.z = f2bf(v1.z); o1.w = f2bf(v1.w);
        *(short4*)&xb[i] = o0; *(short4*)&xb[i + 4] = o1;
        return;
    }
    if (z == 3 && blockIdx.x >= 16) {
        const int idx = blockIdx.y * 16 + (blockIdx.x - 16);
        if (idx >= 80) return;
        const int h = idx / 5, rb = idx % 5;
        const int r = rb * 256 + threadIdx.x;
        if (r >= TBLR) return;
        const float mu = 1.f / (1.f + expf(-mu_raw[h])) + 1e-4f;
        const float Ac = log1pf(expf(sigma_raw[h])) / (2.f * mu);
        const float Cc = log1pf(expf(eta_raw[h])) + log1pf(expf(gamma_raw[h]));
        const float arg = fminf(fmaxf(-mu * (float)(r - 64), -30.f), 0.f);
        const float E   = expf(arg);
        const float V   = fmaf(Ac, 1.f - E * E, Cc);
        tbl[h * TBLR + r] = make_float4(2.f * E, 1.f / V, -32.f * log2f(V), E * E);
        return;
    }
    const float* in; short* out; int R, C;
    if (z < 3) { if (blockIdx.y >= 16) return;
                 in = (z == 0) ? Wq : (z == 1) ? Wk : Wv;
                 out = wt + (size_t)z * 2097152; R = 1024; C = 2048; }
    else       { in = Wo; out = wot; R = 2048; C = 1024; }
    __shared__ float t[64][65];
    const int c0 = blockIdx.x * 64, r0 = blockIdx.y * 64;
    const int tr = threadIdx.x >> 4, tc4 = (threadIdx.x & 15) * 4;
#pragma unroll
    for (int s = 0; s < 4; ++s) {
        const int r = tr + s * 16;
        float4 v = *(const float4*)&in[(size_t)(r0 + r) * C + c0 + tc4];
        t[r][tc4] = v.x; t[r][tc4 + 1] = v.y; t[r][tc4 + 2] = v.z; t[r][tc4 + 3] = v.w;
    }
    __syncthreads();
#pragma unroll
    for (int s = 0; s < 4; ++s) {
        const int oc = tr + s * 16;
        short4 o;
        o.x = f2bf(t[tc4 + 0][oc]); o.y = f2bf(t[tc4 + 1][oc]);
        o.z = f2bf(t[tc4 + 2][oc]); o.w = f2bf(t[tc4 + 3][oc]);
        *(short4*)&out[(size_t)(c0 + oc) * R + r0 + tc4] = o;
    }
}

// ---------------------------------------------------------------------------
// QKV GEMM + fused RoPE rotation/norms. R18 = R6-proven version (B staged via
// LDS). R7's B-direct-to-reg regressed 43->62us: per-lane B loads stride 2KB
// -> ~16 transactions/wave serialized against the barrier (occupancy rose to
// 45% but MfmaUtil fell to 15%, VALU 9% -- pure latency exposure). 64x128
// tile, grid (32,16,3)=1536, LDS 25.3KB, (256,5) -> 5 blocks/CU.
// ---------------------------------------------------------------------------
__global__ __launch_bounds__(256, 5) void gemm_qkv_rot2(
    const short* __restrict__ A, const short* __restrict__ wt,
    const float* __restrict__ omega,
    short* __restrict__ qb, short* __restrict__ kb, short* __restrict__ vtb,
    float* __restrict__ qn_, float* __restrict__ kn_) {
    __shared__ __align__(16) short As[64 * 64];
    __shared__ __align__(16) short Bs[128 * 64];
    __shared__ float sN[4][64];
    const int tid = threadIdx.x;
    const int m0  = blockIdx.x * 64;
    const int h   = blockIdx.y;
    const short* W = wt + (size_t)blockIdx.z * 2097152;

    const short* aP[2]; int aOff[2];
#pragma unroll
    for (int i = 0; i < 2; ++i) {
        const int c   = i * 256 + tid;
        const int row = c >> 3;
        const int src = ((c & 7) ^ (row & 7)) << 3;
        aOff[i] = c * 8;
        aP[i] = A + (size_t)(m0 + row) * 1024 + src;
    }
    const short* bP[4]; int bOff[4];
#pragma unroll
    for (int i = 0; i < 4; ++i) {
        const int c   = i * 256 + tid;
        const int row = c >> 3;
        const int src = ((c & 7) ^ (row & 7)) << 3;
        bOff[i] = c * 8;
        const int t_ = row >> 5, u_ = (row >> 4) & 1, dcol = t_ * 16 + (row & 15);
        bP[i] = W + (size_t)(u_ * 1024 + h * 64 + dcol) * 1024 + src;
    }

    const int lane = tid & 63, w = tid >> 6;
    const int wc = w * 32;
    const int fr = lane & 15;
    const int fo = (lane >> 4) << 3;
    const int sw = (fr & 7) << 3;

    f32x4 acc[4][2];
#pragma unroll
    for (int a = 0; a < 4; ++a)
#pragma unroll
        for (int b = 0; b < 2; ++b) acc[a][b] = (f32x4){0.f, 0.f, 0.f, 0.f};

    for (int k0 = 0; k0 < 1024; k0 += 64) {
#pragma unroll
        for (int i = 0; i < 2; ++i) GLDS16(aP[i] + k0, &As[aOff[i]]);
#pragma unroll
        for (int i = 0; i < 4; ++i) GLDS16(bP[i] + k0, &Bs[bOff[i]]);
        __syncthreads();
#pragma unroll
        for (int ks = 0; ks < 64; ks += 32) {
            bf16x8 af[4], bf[2];
#pragma unroll
            for (int a = 0; a < 4; ++a)
                af[a] = *(const bf16x8*)&As[(a * 16 + fr) * 64 + ((ks + fo) ^ sw)];
#pragma unroll
            for (int b = 0; b < 2; ++b)
                bf[b] = *(const bf16x8*)&Bs[(wc + b * 16 + fr) * 64 + ((ks + fo) ^ sw)];
#pragma unroll
            for (int a = 0; a < 4; ++a)
#pragma unroll
                for (int b = 0; b < 2; ++b)
                    acc[a][b] = __builtin_amdgcn_mfma_f32_16x16x32_bf16(
                        af[a], bf[b], acc[a][b], 0, 0, 0);
        }
        __syncthreads();
    }

    const int quad = lane >> 4, cq = quad * 4, l15 = lane & 15;
    const int bh  = (m0 >> 10) * 16 + h;
    const int nb0 = (m0 & 1023) + cq;

    if (blockIdx.z == 2) {
#pragma unroll
        for (int a = 0; a < 4; ++a) {
#pragma unroll
            for (int b = 0; b < 2; ++b) {
                const int cl = wc + b * 16;
                const int dd = ((cl >> 4) & 1) * 64 + (cl >> 5) * 16 + l15;
                short4 o;
                o.x = f2bf(acc[a][b][0]); o.y = f2bf(acc[a][b][1]);
                o.z = f2bf(acc[a][b][2]); o.w = f2bf(acc[a][b][3]);
                *(short4*)&vtb[((size_t)bh * 128 + dd) * 1024 + nb0 + a * 16] = o;
            }
        }
        return;
    }
    float* nout = (blockIdx.z == 0) ? qn_ : kn_;
    short* obuf = (blockIdx.z == 0) ? qb  : kb;

#pragma unroll
    for (int a = 0; a < 4; ++a) {
        float ns[4] = {0.f, 0.f, 0.f, 0.f};
#pragma unroll
        for (int b = 0; b < 2; ++b)
#pragma unroll
            for (int r = 0; r < 4; ++r)
                ns[r] = fmaf(acc[a][b][r], acc[a][b][r], ns[r]);
#pragma unroll
        for (int m2 = 1; m2 < 16; m2 <<= 1)
#pragma unroll
            for (int r = 0; r < 4; ++r) ns[r] += __shfl_xor(ns[r], m2);
        if (l15 == 0)
#pragma unroll
            for (int r = 0; r < 4; ++r) sN[w][a * 16 + cq + r] = ns[r];
    }
    __syncthreads();
    if (tid < 64)
        nout[(size_t)bh * 1024 + (m0 & 1023) + tid] =
            sN[0][tid] + sN[1][tid] + sN[2][tid] + sN[3][tid];

    {
        const int d = w * 16 + l15;            // complex dim 0..63
        const float om = (d < 32) ? omega[h * 32 + d] : -omega[h * 32 + d - 32];
#pragma unroll
        for (int a = 0; a < 4; ++a) {
#pragma unroll
            for (int r = 0; r < 4; ++r) {
                const int n2 = nb0 + a * 16 + r;
                float sn, cs;
                __sincosf((float)n2 * om, &sn, &cs);
                const float re = acc[a][0][r], im = acc[a][1][r];
                short* orow = obuf + ((size_t)bh * 1024 + n2) * 128;
                orow[d]      = f2bf(re * cs - im * sn);
                orow[64 + d] = f2bf(re * sn + im * cs);
            }
        }
    }
}

// ---------------------------------------------------------------------------
// MFMA flash attention (R17): per-block job LISTS (see tables above). 512
// blocks, each runs 1-2 jobs totaling exactly 8-9 KV tiles; every CU gets
// 16-18 tiles regardless of pairing. Split tiles (it 9..15) emit normalized
// partials + LSE; attn_merge (224 tiles) combines. Softmax diet: MFMA
// ones-column row-sums, exp2/log2 rebase, table folds, defer-max THR=16.
// LDS: Ks 32K + Vs 32K + Ps 9216 + sT 4096 + sKn 512 = 79360 -> 2 blocks/CU.
// ---------------------------------------------------------------------------
__global__ __launch_bounds__(256) void attn_mfma(
    const short* __restrict__ qr, const short* __restrict__ kr,
    const short* __restrict__ vt,
    const float* __restrict__ qn, const float* __restrict__ kn,
    const float4* __restrict__ tbl,
    const float* __restrict__ tau_p, const float* __restrict__ nu_raw,
    short* __restrict__ y, short* __restrict__ po0, float* __restrict__ pml) {
    __shared__ __align__(16) short Ks[2][64 * 128];
    __shared__ __align__(16) short Vs[2][128 * 64];
    __shared__ __align__(16) short Ps[64 * 72];
    __shared__ __align__(16) float4 sT[2][128];
    __shared__ float sKn[2][64];

    const int bx   = blockIdx.x;
    const int xcd  = bx & 7;
    const int rest = bx >> 3;                 // 0..63
    const int bh   = xcd * 4 + (rest & 3);    // 4 bh per XCD (L2 locality)
    const int grp  = rest >> 2;               // 0..15 job-list index
    const int h    = bh & 15;

    const int tid  = threadIdx.x;
    const int lane = tid & 63, w = tid >> 6;
    const int quad = lane >> 4, l15 = lane & 15;

    const float nu     = log1pf(expf(nu_raw[h]));
    const float coef   = -0.5f * tau_p[h] * (nu + 64.0f);
    const float inv_nu = 1.f / nu;

    const short* Qb  = qr + (size_t)bh * NN * 128;
    const short* Kb  = kr + (size_t)bh * NN * 128;
    const short* Vtb = vt + (size_t)bh * 128 * NN;

    const bf16x8 onesv = (bf16x8){0x3F80, 0x3F80, 0x3F80, 0x3F80,
                                  0x3F80, 0x3F80, 0x3F80, 0x3F80};
    const bool has2 = (gIT1[grp] >= 0);

#define STAGE(JT, P) do {                                                     \
        const int j0_ = (JT) * 64, dt0_ = i0 - j0_;                           \
        _Pragma("unroll")                                                     \
        for (int i_ = 0; i_ < 4; ++i_) {                                      \
            const int c_ = i_ * 256 + tid, row_ = c_ >> 4;                    \
            const int src_ = ((c_ & 15) ^ (row_ & 7)) * 8;                    \
            GLDS16(Kb + (size_t)(j0_ + row_) * 128 + src_, &Ks[P][c_ * 8]);   \
        }                                                                     \
        _Pragma("unroll")                                                     \
        for (int i_ = 0; i_ < 4; ++i_) {                                      \
            const int c_ = i_ * 256 + tid, d_ = c_ >> 3;                      \
            const int src_ = ((c_ & 7) ^ (d_ & 7)) * 8;                       \
            GLDS16(Vtb + (size_t)d_ * NN + j0_ + src_, &Vs[P][c_ * 8]);       \
        }                                                                     \
        if (w == 0) {                                                         \
            GLDS16(tbl + h * TBLR + 1 + dt0_ + lane, &sT[P][lane]);           \
            GLDS16(tbl + h * TBLR + 65 + dt0_ + lane, &sT[P][64 + lane]);     \
        } else if (w == 1) {                                                  \
            GLDS4(kn + (size_t)bh * NN + j0_ + lane, &sKn[P][lane]);          \
        }                                                                     \
    } while (0)

    for (int jj = 0; jj < 2; ++jj) {
        int it, j0j, j1j, psel;
        if (jj == 0) {
            it = gIT0[grp]; j0j = gJ00[grp]; j1j = gJ10[grp]; psel = gPS0[grp];
        } else {
            if (!has2) break;
            it = gIT1[grp]; j0j = 0; j1j = it; psel = 0;
        }
        const int i0 = it * 64;
        const int pq = bh * 7 + (it - 9);     // partial slot (psel != 0 only)

        bf16x8 qf[4];
        const int arow = i0 + w * 16 + l15;
#pragma unroll
        for (int ks = 0; ks < 4; ++ks)
            qf[ks] = *(const bf16x8*)&Qb[(size_t)arow * 128 + ks * 32 + quad * 8];

        float mrow[4];
        f32x4 o[8];
        f32x4 o9 = (f32x4){0.f, 0.f, 0.f, 0.f};  // row-sums via ones-column
#pragma unroll
        for (int r = 0; r < 4; ++r) mrow[r] = -INFINITY;
#pragma unroll
        for (int s = 0; s < 8; ++s) o[s] = (f32x4){0.f, 0.f, 0.f, 0.f};
        float qn4[4];
#pragma unroll
        for (int r = 0; r < 4; ++r)
            qn4[r] = qn[(size_t)bh * NN + i0 + w * 16 + quad * 4 + r];

        STAGE(j0j, 0);
        __syncthreads();

        for (int jt = j0j; jt <= j1j; ++jt) {
            const int p = (jt - j0j) & 1;
            if (jt < j1j) STAGE(jt + 1, 1 - p);  // async prefetch; drained at barrier

            f32x4 sAcc[4];
#pragma unroll
            for (int s = 0; s < 4; ++s) sAcc[s] = (f32x4){0.f, 0.f, 0.f, 0.f};
#pragma unroll
            for (int ks = 0; ks < 4; ++ks) {
#pragma unroll
                for (int s = 0; s < 4; ++s) {
                    const int brow = s * 16 + l15;
                    bf16x8 bK = *(const bf16x8*)&Ks[p][brow * 128 +
                                                      (((ks * 4 + quad) ^ (brow & 7)) * 8)];
                    sAcc[s] = __builtin_amdgcn_mfma_f32_16x16x32_bf16(qf[ks], bK, sAcc[s], 0, 0, 0);
                }
            }

            float al[4];
            bool anyr = false;
#pragma unroll
            for (int r = 0; r < 4; ++r) {
                const int row = w * 16 + quad * 4 + r;
                float lg[4];
#pragma unroll
                for (int s = 0; s < 4; ++s) {
                    const int col = s * 16 + l15;
                    const float4 T = sT[p][row - col + 63];
                    const float sv = sAcc[s][r];
                    const float t1 = fmaf(T.w, sKn[p][col], qn4[r]);     // qn + E^2*kn
                    const float maha = fmaxf(fmaf(-T.x, sv, t1), 0.f) * T.y;
                    float v = fmaf(coef, flog2(fmaf(maha, inv_nu, 1.f)), T.z);
                    if (jt == it && col > row) v = -INFINITY;
                    lg[s] = v;
                }
                float mx = fmaxf(fmaxf(lg[0], lg[1]), fmaxf(lg[2], lg[3]));
                mx = fmaxf(mx, __shfl_xor(mx, 1));
                mx = fmaxf(mx, __shfl_xor(mx, 2));
                mx = fmaxf(mx, __shfl_xor(mx, 4));
                mx = fmaxf(mx, __shfl_xor(mx, 8));
                const bool resc = mx > mrow[r] + 16.f;   // defer-max
                const float mu_ = resc ? mx : mrow[r];
                al[r] = resc ? fexp2(mrow[r] - mx) : 1.f;
                mrow[r] = mu_;
                anyr = anyr || resc;
#pragma unroll
                for (int s = 0; s < 4; ++s) {
                    const float pv = fexp2(lg[s] - mu_);
                    Ps[row * 72 + s * 16 + l15] = f2bf(pv);
                }
            }
            if (anyr) {
#pragma unroll
                for (int s = 0; s < 8; ++s)
#pragma unroll
                    for (int r = 0; r < 4; ++r) o[s][r] *= al[r];
#pragma unroll
                for (int r = 0; r < 4; ++r) o9[r] *= al[r];
            }

#pragma unroll
            for (int jc = 0; jc < 2; ++jc) {
                bf16x8 aP = *(const bf16x8*)&Ps[(w * 16 + l15) * 72 + jc * 32 + quad * 8];
#pragma unroll
                for (int sub = 0; sub < 8; ++sub) {
                    const int d = sub * 16 + l15;
                    bf16x8 bV = *(const bf16x8*)&Vs[p][d * 64 + (((jc * 4 + quad) ^ (d & 7)) * 8)];
                    o[sub] = __builtin_amdgcn_mfma_f32_16x16x32_bf16(aP, bV, o[sub], 0, 0, 0);
                }
                o9 = __builtin_amdgcn_mfma_f32_16x16x32_bf16(aP, onesv, o9, 0, 0, 0);
            }
            if (jt < j1j) __syncthreads();
        }

        // Epilogue: direct -> y; split -> normalized partial (o/l) + LSE.
        short* dst = (psel == 1) ? po0 : y;
        const size_t rbase = (psel == 1) ? (size_t)pq * 64 : ((size_t)bh * NN + i0);
#pragma unroll
        for (int r = 0; r < 4; ++r) {
            const int lrow = w * 16 + quad * 4 + r;
            const float inv = 1.f / o9[r];
            const size_t base = (rbase + lrow) * 128;
#pragma unroll
            for (int sub = 0; sub < 8; ++sub)
                dst[base + sub * 16 + l15] = f2bf(o[sub][r] * inv);
            if (psel != 0 && l15 == 0)
                pml[(pq * 2 + (psel - 1)) * 64 + lrow] = mrow[r] + flog2(o9[r]);
        }
        if (jj == 0 && has2) __syncthreads();   // protect LDS before job1 restages
    }
#undef STAGE
}

// ---------------------------------------------------------------------------
// LSE merge of split q-tiles (it 9..15 per bh): y = (o1n*w1 + o2n*w2)/(w1+w2).
// 224 blocks x 256 threads; in-place on y.
// ---------------------------------------------------------------------------
__global__ __launch_bounds__(256) void attn_merge(
    const short* __restrict__ po0, const float* __restrict__ pml,
    short* __restrict__ y) {
    const int qs = blockIdx.x;                // 0..223: bh*7 + (it-9)
    const int bh = qs / 7, it = qs % 7 + 9;
    const int t = threadIdx.x;
    const int row = t >> 2, dc = (t & 3) * 32;
    const float m1 = pml[(qs * 2 + 0) * 64 + row];
    const float m2 = pml[(qs * 2 + 1) * 64 + row];
    const float mx = fmaxf(m1, m2);
    const float w1 = fexp2(m1 - mx), w2 = fexp2(m2 - mx);
    const float inv = 1.f / (w1 + w2);
    const float a = w1 * inv, b = w2 * inv;
    const short* s1 = po0 + ((size_t)qs * 64 + row) * 128 + dc;
    short*       s2 = y + ((size_t)bh * NN + it * 64 + row) * 128 + dc;
#pragma unroll
    for (int i = 0; i < 32; i += 8) {
        bf16x8 v1 = *(const bf16x8*)(s1 + i);
        bf16x8 v2 = *(const bf16x8*)(s2 + i);
        bf16x8 ov;
#pragma unroll
        for (int k = 0; k < 8; ++k)
            ov[k] = f2bf(a * bf2f(v1[k]) + b * bf2f(v2[k]));
        *(bf16x8*)(s2 + i) = ov;
    }
}

// ---------------------------------------------------------------------------
// Output GEMM: out[2048][1024] = y @ Wo. 64x64 tiles, grid (32,16) = 512
// blocks, BK=64, direct f32 stores, 2-phase double-buffer. LDS 32KB.
// ---------------------------------------------------------------------------
__global__ __launch_bounds__(256) void gemm_out64(
    const short* __restrict__ yb, const short* __restrict__ wot,
    float* __restrict__ out) {
    __shared__ __align__(16) short As[2][64 * 64];
    __shared__ __align__(16) short Bs[2][64 * 64];
    const int tid = threadIdx.x;
    const int m0  = blockIdx.x * 64;
    const int n0  = blockIdx.y * 64;
    const int bb  = m0 >> 10;

    int aPre[2], aOff[2]; const short* bP[2];
#pragma unroll
    for (int i = 0; i < 2; ++i) {
        const int c = i * 256 + tid, row = c >> 3;
        const int src = ((c & 7) ^ (row & 7)) << 3;
        aPre[i] = ((m0 & 1023) + row) * 128 + src;
        bP[i] = wot + (size_t)(n0 + row) * 2048 + src;
        aOff[i] = c * 8;
    }

    const int lane = tid & 63, w = tid >> 6;
    const int wr = (w >> 1) * 32, wc = (w & 1) * 32;
    const int fr = lane & 15;
    const int fo = (lane >> 4) << 3;
    const int sw = (fr & 7) << 3;

    f32x4 acc[2][2];
#pragma unroll
    for (int a = 0; a < 2; ++a)
#pragma unroll
        for (int b = 0; b < 2; ++b) acc[a][b] = (f32x4){0.f, 0.f, 0.f, 0.f};

#define OSTAGE(KT, P) do {                                                    \
        const int k0_ = (KT) * 64;                                            \
        const int hh_ = (k0_ >> 6) & 15, im_ = k0_ >> 10;                     \
        const short* ab_ = yb + ((size_t)(bb * 16 + hh_) << 17) + im_ * 64;   \
        _Pragma("unroll")                                                     \
        for (int i_ = 0; i_ < 2; ++i_) GLDS16(ab_ + aPre[i_], &As[P][aOff[i_]]); \
        _Pragma("unroll")                                                     \
        for (int i_ = 0; i_ < 2; ++i_) GLDS16(bP[i_] + k0_, &Bs[P][aOff[i_]]);   \
    } while (0)

    OSTAGE(0, 0);
    __syncthreads();

    for (int kt = 0; kt < 32; ++kt) {
        const int p = kt & 1;
        if (kt < 31) OSTAGE(kt + 1, 1 - p);
#pragma unroll
        for (int ks = 0; ks < 64; ks += 32) {
            bf16x8 af[2], bf[2];
#pragma unroll
            for (int a = 0; a < 2; ++a)
                af[a] = *(const bf16x8*)&As[p][(wr + a * 16 + fr) * 64 + ((ks + fo) ^ sw)];
#pragma unroll
            for (int b = 0; b < 2; ++b)
                bf[b] = *(const bf16x8*)&Bs[p][(wc + b * 16 + fr) * 64 + ((ks + fo) ^ sw)];
#pragma unroll
            for (int a = 0; a < 2; ++a)
#pragma unroll
                for (int b = 0; b < 2; ++b)
                    acc[a][b] = __builtin_amdgcn_mfma_f32_16x16x32_bf16(
                        af[a], bf[b], acc[a][b], 0, 0, 0);
        }
        if (kt < 31) __syncthreads();
    }
#undef OSTAGE

    const int cq = (lane >> 4) * 4, l15 = lane & 15;
#pragma unroll
    for (int a = 0; a < 2; ++a)
#pragma unroll
        for (int b = 0; b < 2; ++b)
#pragma unroll
            for (int r = 0; r < 4; ++r)
                out[(size_t)(m0 + wr + a * 16 + cq + r) * 1024 +
                    (n0 + wc + b * 16 + l15)] = acc[a][b][r];
}

// ---------------------------------------------------------------------------
extern "C" void kernel_launch(void* const* d_in, const int* in_sizes, int n_in,
                              void* d_out, int out_size, void* d_ws, size_t ws_size,
                              hipStream_t stream) {
    const float* x         = (const float*)d_in[0];
    const float* Wq        = (const float*)d_in[1];
    const float* Wk        = (const float*)d_in[2];
    const float* Wv        = (const float*)d_in[3];
    const float* Wo        = (const float*)d_in[4];
    const float* omega     = (const float*)d_in[5];
    const float* mu_raw    = (const float*)d_in[6];
    const float* sigma_raw = (const float*)d_in[7];
    const float* eta_raw   = (const float*)d_in[8];
    const float* gamma_raw = (const float*)d_in[9];
    const float* tau       = (const float*)d_in[10];
    const float* nu_raw    = (const float*)d_in[11];
    float* out = (float*)d_out;

    short*  qb  = (short*)d_ws;
    short*  kb  = qb + PK;
    short*  vtb = kb + PK;
    float*  qn  = (float*)(vtb + PK);
    float*  kn  = qn + 32768;
    float4* tbl = (float4*)(kn + 32768);
    short*  wot = (short*)(tbl + HH * TBLR);
    short*  wt  = wot + 2097152;
    short*  xb  = wt + 3 * 2097152;
    short*  yb  = wt;                       // alias (wt dead after qkv)
    short*  po0 = wt + 4194304;             // first-half partials (wt tail)
    float*  pml = (float*)xb;               // per-row LSE partials (xb dead after qkv)

    prep<<<dim3(32, 32, 5), 256, 0, stream>>>(
        x, Wq, Wk, Wv, Wo, mu_raw, sigma_raw, eta_raw, gamma_raw,
        xb, wt, wot, tbl);
    gemm_qkv_rot2<<<dim3(32, 16, 3), 256, 0, stream>>>(
        xb, wt, omega, qb, kb, vtb, qn, kn);
    attn_mfma<<<dim3(512), 256, 0, stream>>>(
        qb, kb, vtb, qn, kn, tbl, tau, nu_raw, yb, po0, pml);
    attn_merge<<<dim3(224), 256, 0, stream>>>(po0, pml, yb);
    gemm_out64<<<dim3(32, 16), 256, 0, stream>>>(yb, wot, out);
}

// Round 9
// 190.490 us; speedup vs baseline: 1.1399x; 1.0564x over previous
//
#include <hip/hip_runtime.h>
#include <math.h>

// Problem constants (B=2, N=1024, DE=1024, H=16, DH=64 complex dims/head)
#define BB      2
#define NN      1024
#define DE_     1024
#define HH      16
#define TWO_DK  2048
#define PK      4194304     // B*H*N*128 packed elements per q/k/v stream
#define TBLR    1092        // per-head table entries: dt in [-64, 1028)

typedef float f32x4  __attribute__((ext_vector_type(4)));
typedef short bf16x8 __attribute__((ext_vector_type(8)));

__device__ __forceinline__ short f2bf(float f) {
    unsigned u = __float_as_uint(f);
    unsigned r = (u + 0x7fffu + ((u >> 16) & 1u)) >> 16;   // RNE
    return (short)r;
}
__device__ __forceinline__ float bf2f(short v) {
    return __uint_as_float(((unsigned)(unsigned short)v) << 16);
}

// raw v_exp_f32 / v_log_f32 (both base-2 on AMD HW). HIP lacks __exp2f/__log2f.
__device__ __forceinline__ float fexp2(float x) { return __builtin_amdgcn_exp2f(x); }
__device__ __forceinline__ float flog2(float x) { return __builtin_amdgcn_logf(x); }

#define GLDS16(g, l) __builtin_amdgcn_global_load_lds(                        \
    (const __attribute__((address_space(1))) unsigned int*)(g),               \
    (__attribute__((address_space(3))) unsigned int*)(l), 16, 0, 0)
#define GLDS4(g, l) __builtin_amdgcn_global_load_lds(                         \
    (const __attribute__((address_space(1))) unsigned int*)(g),               \
    (__attribute__((address_space(3))) unsigned int*)(l), 4, 0, 0)

// ---------------------------------------------------------------------------
// R14 job tables (restored for R19): per bh 24 jobs -- q-tiles 0..7 single
// (lengths 1..8), q-tiles 8..15 split at h=(it+2)/2 into halves (max length
// 8, first half never reaches the diagonal). Ranks longest-first so HW
// dispatch+refill approximates LPT over 768 resident slots (3 blocks/CU with
// the R19 single-buffered 43.5KB LDS). psel: 0=direct y write, 1=first-half
// partial, 2=second-half partial (merged by attn_merge).
// ---------------------------------------------------------------------------
__constant__ int jIT[24] = {7,14,15,15, 6,12,13,13,14, 5,10,11,11,12,
                            4, 8, 9, 9,10, 3, 8, 2, 1, 0};
__constant__ int jJ0[24] = {0, 0, 0, 8, 0, 0, 0, 7, 8, 0, 0, 0, 6, 7,
                            0, 0, 0, 5, 6, 0, 5, 0, 0, 0};
__constant__ int jJ1[24] = {7, 7, 7,15, 6, 6, 6,13,14, 5, 5, 5,11,12,
                            4, 4, 4, 9,10, 3, 8, 2, 1, 0};
__constant__ int jPS[24] = {0, 1, 1, 2, 0, 1, 1, 2, 2, 0, 1, 1, 2, 2,
                            0, 1, 1, 2, 2, 0, 2, 0, 0, 0};

// ---------------------------------------------------------------------------
// prep: z=0..2 transpose Wq/Wk/Wv -> wt[n][k] bf16; z=3,bx<16 transpose Wo;
//       z=3,bx>=16 decay tables; z=4 x fp32->bf16.
// Table entries: x = 2*E, y = 1/V, z = -32*log2(V), w = E*E (log2 units).
// ---------------------------------------------------------------------------
__global__ __launch_bounds__(256) void prep(
    const float* __restrict__ x,
    const float* __restrict__ Wq, const float* __restrict__ Wk,
    const float* __restrict__ Wv, const float* __restrict__ Wo,
    const float* __restrict__ mu_raw, const float* __restrict__ sigma_raw,
    const float* __restrict__ eta_raw, const float* __restrict__ gamma_raw,
    short* __restrict__ xb, short* __restrict__ wt, short* __restrict__ wot,
    float4* __restrict__ tbl) {
    const int z = blockIdx.z;
    if (z == 4) {
        const int flat = blockIdx.y * 32 + blockIdx.x;
        const int i = (flat * 256 + threadIdx.x) * 8;
        float4 v0 = *(const float4*)&x[i];
        float4 v1 = *(const float4*)&x[i + 4];
        short4 o0, o1;
        o0.x = f2bf(v0.x); o0.y = f2bf(v0.y); o0.z = f2bf(v0.z); o0.w = f2bf(v0.w);
        o1.x = f2bf(v1.x); o1.y = f2bf(v1.y); o1.z = f2bf(v1.z); o1.w = f2bf(v1.w);
        *(short4*)&xb[i] = o0; *(short4*)&xb[i + 4] = o1;
        return;
    }
    if (z == 3 && blockIdx.x >= 16) {
        const int idx = blockIdx.y * 16 + (blockIdx.x - 16);
        if (idx >= 80) return;
        const int h = idx / 5, rb = idx % 5;
        const int r = rb * 256 + threadIdx.x;
        if (r >= TBLR) return;
        const float mu = 1.f / (1.f + expf(-mu_raw[h])) + 1e-4f;
        const float Ac = log1pf(expf(sigma_raw[h])) / (2.f * mu);
        const float Cc = log1pf(expf(eta_raw[h])) + log1pf(expf(gamma_raw[h]));
        const float arg = fminf(fmaxf(-mu * (float)(r - 64), -30.f), 0.f);
        const float E   = expf(arg);
        const float V   = fmaf(Ac, 1.f - E * E, Cc);
        tbl[h * TBLR + r] = make_float4(2.f * E, 1.f / V, -32.f * log2f(V), E * E);
        return;
    }
    const float* in; short* out; int R, C;
    if (z < 3) { if (blockIdx.y >= 16) return;
                 in = (z == 0) ? Wq : (z == 1) ? Wk : Wv;
                 out = wt + (size_t)z * 2097152; R = 1024; C = 2048; }
    else       { in = Wo; out = wot; R = 2048; C = 1024; }
    __shared__ float t[64][65];
    const int c0 = blockIdx.x * 64, r0 = blockIdx.y * 64;
    const int tr = threadIdx.x >> 4, tc4 = (threadIdx.x & 15) * 4;
#pragma unroll
    for (int s = 0; s < 4; ++s) {
        const int r = tr + s * 16;
        float4 v = *(const float4*)&in[(size_t)(r0 + r) * C + c0 + tc4];
        t[r][tc4] = v.x; t[r][tc4 + 1] = v.y; t[r][tc4 + 2] = v.z; t[r][tc4 + 3] = v.w;
    }
    __syncthreads();
#pragma unroll
    for (int s = 0; s < 4; ++s) {
        const int oc = tr + s * 16;
        short4 o;
        o.x = f2bf(t[tc4 + 0][oc]); o.y = f2bf(t[tc4 + 1][oc]);
        o.z = f2bf(t[tc4 + 2][oc]); o.w = f2bf(t[tc4 + 3][oc]);
        *(short4*)&out[(size_t)(c0 + oc) * R + r0 + tc4] = o;
    }
}

// ---------------------------------------------------------------------------
// QKV GEMM + fused RoPE rotation/norms. R6-proven (best measured <=43.4us):
// 64x128 tile, B staged via LDS, grid (32,16,3)=1536, LDS 25.3KB, (256,5)
// -> 5 blocks/CU. Left untouched in R19.
// ---------------------------------------------------------------------------
__global__ __launch_bounds__(256, 5) void gemm_qkv_rot2(
    const short* __restrict__ A, const short* __restrict__ wt,
    const float* __restrict__ omega,
    short* __restrict__ qb, short* __restrict__ kb, short* __restrict__ vtb,
    float* __restrict__ qn_, float* __restrict__ kn_) {
    __shared__ __align__(16) short As[64 * 64];
    __shared__ __align__(16) short Bs[128 * 64];
    __shared__ float sN[4][64];
    const int tid = threadIdx.x;
    const int m0  = blockIdx.x * 64;
    const int h   = blockIdx.y;
    const short* W = wt + (size_t)blockIdx.z * 2097152;

    const short* aP[2]; int aOff[2];
#pragma unroll
    for (int i = 0; i < 2; ++i) {
        const int c   = i * 256 + tid;
        const int row = c >> 3;
        const int src = ((c & 7) ^ (row & 7)) << 3;
        aOff[i] = c * 8;
        aP[i] = A + (size_t)(m0 + row) * 1024 + src;
    }
    const short* bP[4]; int bOff[4];
#pragma unroll
    for (int i = 0; i < 4; ++i) {
        const int c   = i * 256 + tid;
        const int row = c >> 3;
        const int src = ((c & 7) ^ (row & 7)) << 3;
        bOff[i] = c * 8;
        const int t_ = row >> 5, u_ = (row >> 4) & 1, dcol = t_ * 16 + (row & 15);
        bP[i] = W + (size_t)(u_ * 1024 + h * 64 + dcol) * 1024 + src;
    }

    const int lane = tid & 63, w = tid >> 6;
    const int wc = w * 32;
    const int fr = lane & 15;
    const int fo = (lane >> 4) << 3;
    const int sw = (fr & 7) << 3;

    f32x4 acc[4][2];
#pragma unroll
    for (int a = 0; a < 4; ++a)
#pragma unroll
        for (int b = 0; b < 2; ++b) acc[a][b] = (f32x4){0.f, 0.f, 0.f, 0.f};

    for (int k0 = 0; k0 < 1024; k0 += 64) {
#pragma unroll
        for (int i = 0; i < 2; ++i) GLDS16(aP[i] + k0, &As[aOff[i]]);
#pragma unroll
        for (int i = 0; i < 4; ++i) GLDS16(bP[i] + k0, &Bs[bOff[i]]);
        __syncthreads();
#pragma unroll
        for (int ks = 0; ks < 64; ks += 32) {
            bf16x8 af[4], bf[2];
#pragma unroll
            for (int a = 0; a < 4; ++a)
                af[a] = *(const bf16x8*)&As[(a * 16 + fr) * 64 + ((ks + fo) ^ sw)];
#pragma unroll
            for (int b = 0; b < 2; ++b)
                bf[b] = *(const bf16x8*)&Bs[(wc + b * 16 + fr) * 64 + ((ks + fo) ^ sw)];
#pragma unroll
            for (int a = 0; a < 4; ++a)
#pragma unroll
                for (int b = 0; b < 2; ++b)
                    acc[a][b] = __builtin_amdgcn_mfma_f32_16x16x32_bf16(
                        af[a], bf[b], acc[a][b], 0, 0, 0);
        }
        __syncthreads();
    }

    const int quad = lane >> 4, cq = quad * 4, l15 = lane & 15;
    const int bh  = (m0 >> 10) * 16 + h;
    const int nb0 = (m0 & 1023) + cq;

    if (blockIdx.z == 2) {
#pragma unroll
        for (int a = 0; a < 4; ++a) {
#pragma unroll
            for (int b = 0; b < 2; ++b) {
                const int cl = wc + b * 16;
                const int dd = ((cl >> 4) & 1) * 64 + (cl >> 5) * 16 + l15;
                short4 o;
                o.x = f2bf(acc[a][b][0]); o.y = f2bf(acc[a][b][1]);
                o.z = f2bf(acc[a][b][2]); o.w = f2bf(acc[a][b][3]);
                *(short4*)&vtb[((size_t)bh * 128 + dd) * 1024 + nb0 + a * 16] = o;
            }
        }
        return;
    }
    float* nout = (blockIdx.z == 0) ? qn_ : kn_;
    short* obuf = (blockIdx.z == 0) ? qb  : kb;

#pragma unroll
    for (int a = 0; a < 4; ++a) {
        float ns[4] = {0.f, 0.f, 0.f, 0.f};
#pragma unroll
        for (int b = 0; b < 2; ++b)
#pragma unroll
            for (int r = 0; r < 4; ++r)
                ns[r] = fmaf(acc[a][b][r], acc[a][b][r], ns[r]);
#pragma unroll
        for (int m2 = 1; m2 < 16; m2 <<= 1)
#pragma unroll
            for (int r = 0; r < 4; ++r) ns[r] += __shfl_xor(ns[r], m2);
        if (l15 == 0)
#pragma unroll
            for (int r = 0; r < 4; ++r) sN[w][a * 16 + cq + r] = ns[r];
    }
    __syncthreads();
    if (tid < 64)
        nout[(size_t)bh * 1024 + (m0 & 1023) + tid] =
            sN[0][tid] + sN[1][tid] + sN[2][tid] + sN[3][tid];

    {
        const int d = w * 16 + l15;            // complex dim 0..63
        const float om = (d < 32) ? omega[h * 32 + d] : -omega[h * 32 + d - 32];
#pragma unroll
        for (int a = 0; a < 4; ++a) {
#pragma unroll
            for (int r = 0; r < 4; ++r) {
                const int n2 = nb0 + a * 16 + r;
                float sn, cs;
                __sincosf((float)n2 * om, &sn, &cs);
                const float re = acc[a][0][r], im = acc[a][1][r];
                short* orow = obuf + ((size_t)bh * 1024 + n2) * 128;
                orow[d]      = f2bf(re * cs - im * sn);
                orow[64 + d] = f2bf(re * sn + im * cs);
            }
        }
    }
}

// ---------------------------------------------------------------------------
// MFMA flash attention (R19): SINGLE-BUFFERED LDS + 3 blocks/CU. R6's lesson
// applied to attn: cross-block overlap beats intra-block dbuf. LDS drops
// 79.4KB -> 43.5KB (Ks 16K + Vs 16K + Ps 9.2K + sT 2K + sKn 256B) -> 3
// blocks/CU; the 768-job R14 split-KV tables fill the extra slots (max 8
// tiles/job, LPT-ordered). Per iter: STAGE -> barrier -> compute -> barrier;
// the exposed staging (~550cyc) hides under the other 2 blocks' compute.
// Softmax diet unchanged: MFMA ones-column row-sums, exp2/log2 rebase,
// table folds, defer-max THR=16.
// ---------------------------------------------------------------------------
__global__ __launch_bounds__(256) void attn_mfma(
    const short* __restrict__ qr, const short* __restrict__ kr,
    const short* __restrict__ vt,
    const float* __restrict__ qn, const float* __restrict__ kn,
    const float4* __restrict__ tbl,
    const float* __restrict__ tau_p, const float* __restrict__ nu_raw,
    short* __restrict__ y, short* __restrict__ po0, float* __restrict__ pml) {
    __shared__ __align__(16) short Ks[64 * 128];
    __shared__ __align__(16) short Vs[128 * 64];
    __shared__ __align__(16) short Ps[64 * 72];
    __shared__ __align__(16) float4 sT[128];
    __shared__ float sKn[64];

    const int bx   = blockIdx.x;
    const int xcd  = bx & 7;
    const int rest = bx >> 3;                 // 0..95
    const int jrk  = rest >> 2;               // 0..23 longest-first
    const int bh   = xcd * 4 + (rest & 3);    // 4 bh per XCD (L2 locality)
    const int h    = bh & 15;
    const int it   = jIT[jrk];
    const int j0j  = jJ0[jrk];
    const int j1j  = jJ1[jrk];
    const int psel = jPS[jrk];                // 0 direct, 1 half0, 2 half1
    const int i0   = it * 64;
    const int pq   = bh * 8 + (it - 8);       // partial slot (psel != 0 only)

    const int tid  = threadIdx.x;
    const int lane = tid & 63, w = tid >> 6;
    const int quad = lane >> 4, l15 = lane & 15;

    const float nu     = log1pf(expf(nu_raw[h]));
    const float coef   = -0.5f * tau_p[h] * (nu + 64.0f);
    const float inv_nu = 1.f / nu;

    const short* Qb  = qr + (size_t)bh * NN * 128;
    const short* Kb  = kr + (size_t)bh * NN * 128;
    const short* Vtb = vt + (size_t)bh * 128 * NN;

#define STAGE(JT) do {                                                        \
        const int j0_ = (JT) * 64, dt0_ = i0 - j0_;                           \
        _Pragma("unroll")                                                     \
        for (int i_ = 0; i_ < 4; ++i_) {                                      \
            const int c_ = i_ * 256 + tid, row_ = c_ >> 4;                    \
            const int src_ = ((c_ & 15) ^ (row_ & 7)) * 8;                    \
            GLDS16(Kb + (size_t)(j0_ + row_) * 128 + src_, &Ks[c_ * 8]);      \
        }                                                                     \
        _Pragma("unroll")                                                     \
        for (int i_ = 0; i_ < 4; ++i_) {                                      \
            const int c_ = i_ * 256 + tid, d_ = c_ >> 3;                      \
            const int src_ = ((c_ & 7) ^ (d_ & 7)) * 8;                       \
            GLDS16(Vtb + (size_t)d_ * NN + j0_ + src_, &Vs[c_ * 8]);          \
        }                                                                     \
        if (w == 0) {                                                         \
            GLDS16(tbl + h * TBLR + 1 + dt0_ + lane, &sT[lane]);              \
            GLDS16(tbl + h * TBLR + 65 + dt0_ + lane, &sT[64 + lane]);        \
        } else if (w == 1) {                                                  \
            GLDS4(kn + (size_t)bh * NN + j0_ + lane, &sKn[lane]);             \
        }                                                                     \
    } while (0)

    bf16x8 qf[4];
    const int arow = i0 + w * 16 + l15;
#pragma unroll
    for (int ks = 0; ks < 4; ++ks)
        qf[ks] = *(const bf16x8*)&Qb[(size_t)arow * 128 + ks * 32 + quad * 8];

    float mrow[4];
    f32x4 o[8];
    f32x4 o9 = (f32x4){0.f, 0.f, 0.f, 0.f};     // row-sums (softmax denom) via ones-column
#pragma unroll
    for (int r = 0; r < 4; ++r) mrow[r] = -INFINITY;
#pragma unroll
    for (int s = 0; s < 8; ++s) o[s] = (f32x4){0.f, 0.f, 0.f, 0.f};
    float qn4[4];
#pragma unroll
    for (int r = 0; r < 4; ++r)
        qn4[r] = qn[(size_t)bh * NN + i0 + w * 16 + quad * 4 + r];

    const bf16x8 onesv = (bf16x8){0x3F80, 0x3F80, 0x3F80, 0x3F80,
                                  0x3F80, 0x3F80, 0x3F80, 0x3F80};

    for (int jt = j0j; jt <= j1j; ++jt) {
        STAGE(jt);
        __syncthreads();                      // drain staging before reads

        f32x4 sAcc[4];
#pragma unroll
        for (int s = 0; s < 4; ++s) sAcc[s] = (f32x4){0.f, 0.f, 0.f, 0.f};
#pragma unroll
        for (int ks = 0; ks < 4; ++ks) {
#pragma unroll
            for (int s = 0; s < 4; ++s) {
                const int brow = s * 16 + l15;
                bf16x8 bK = *(const bf16x8*)&Ks[brow * 128 +
                                                (((ks * 4 + quad) ^ (brow & 7)) * 8)];
                sAcc[s] = __builtin_amdgcn_mfma_f32_16x16x32_bf16(qf[ks], bK, sAcc[s], 0, 0, 0);
            }
        }

        float al[4];
        bool anyr = false;
#pragma unroll
        for (int r = 0; r < 4; ++r) {
            const int row = w * 16 + quad * 4 + r;
            float lg[4];
#pragma unroll
            for (int s = 0; s < 4; ++s) {
                const int col = s * 16 + l15;
                const float4 T = sT[row - col + 63];
                const float sv = sAcc[s][r];
                const float t1 = fmaf(T.w, sKn[col], qn4[r]);        // qn + E^2*kn
                const float maha = fmaxf(fmaf(-T.x, sv, t1), 0.f) * T.y;
                float v = fmaf(coef, flog2(fmaf(maha, inv_nu, 1.f)), T.z);
                if (jt == it && col > row) v = -INFINITY;
                lg[s] = v;
            }
            float mx = fmaxf(fmaxf(lg[0], lg[1]), fmaxf(lg[2], lg[3]));
            mx = fmaxf(mx, __shfl_xor(mx, 1));
            mx = fmaxf(mx, __shfl_xor(mx, 2));
            mx = fmaxf(mx, __shfl_xor(mx, 4));
            mx = fmaxf(mx, __shfl_xor(mx, 8));
            const bool resc = mx > mrow[r] + 16.f;   // defer-max
            const float mu_ = resc ? mx : mrow[r];
            al[r] = resc ? fexp2(mrow[r] - mx) : 1.f;
            mrow[r] = mu_;
            anyr = anyr || resc;
#pragma unroll
            for (int s = 0; s < 4; ++s) {
                const float pv = fexp2(lg[s] - mu_);
                Ps[row * 72 + s * 16 + l15] = f2bf(pv);
            }
        }
        if (anyr) {
#pragma unroll
            for (int s = 0; s < 8; ++s)
#pragma unroll
                for (int r = 0; r < 4; ++r) o[s][r] *= al[r];
#pragma unroll
            for (int r = 0; r < 4; ++r) o9[r] *= al[r];
        }

#pragma unroll
        for (int jc = 0; jc < 2; ++jc) {
            bf16x8 aP = *(const bf16x8*)&Ps[(w * 16 + l15) * 72 + jc * 32 + quad * 8];
#pragma unroll
            for (int sub = 0; sub < 8; ++sub) {
                const int d = sub * 16 + l15;
                bf16x8 bV = *(const bf16x8*)&Vs[d * 64 + (((jc * 4 + quad) ^ (d & 7)) * 8)];
                o[sub] = __builtin_amdgcn_mfma_f32_16x16x32_bf16(aP, bV, o[sub], 0, 0, 0);
            }
            o9 = __builtin_amdgcn_mfma_f32_16x16x32_bf16(aP, onesv, o9, 0, 0, 0);
        }
        if (jt < j1j) __syncthreads();        // protect LDS before next STAGE
    }
#undef STAGE

    // Epilogue: direct jobs -> y; split jobs -> normalized partial (o/l) with
    // per-row LSE (m + log2(l)). half0 -> po0 slot; half1 -> y slot in place.
    short* dst = (psel == 1) ? po0 : y;
    const size_t rbase = (psel == 1) ? (size_t)pq * 64 : ((size_t)bh * NN + i0);
#pragma unroll
    for (int r = 0; r < 4; ++r) {
        const int lrow = w * 16 + quad * 4 + r;
        const float inv = 1.f / o9[r];
        const size_t base = (rbase + lrow) * 128;
#pragma unroll
        for (int sub = 0; sub < 8; ++sub)
            dst[base + sub * 16 + l15] = f2bf(o[sub][r] * inv);
        if (psel != 0 && l15 == 0)
            pml[(pq * 2 + (psel - 1)) * 64 + lrow] = mrow[r] + flog2(o9[r]);
    }
}

// ---------------------------------------------------------------------------
// LSE merge of split q-tiles: y = (o1n*w1 + o2n*w2)/(w1+w2), w_i = 2^(m_i-mx).
// 256 blocks (one per split q-tile) x 256 threads; in-place on y.
// ---------------------------------------------------------------------------
__global__ __launch_bounds__(256) void attn_merge(
    const short* __restrict__ po0, const float* __restrict__ pml,
    short* __restrict__ y) {
    const int qs = blockIdx.x;                // 0..255: bh*8 + (it-8)
    const int bh = qs >> 3, it = (qs & 7) + 8;
    const int t = threadIdx.x;
    const int row = t >> 2, dc = (t & 3) * 32;
    const float m1 = pml[(qs * 2 + 0) * 64 + row];
    const float m2 = pml[(qs * 2 + 1) * 64 + row];
    const float mx = fmaxf(m1, m2);
    const float w1 = fexp2(m1 - mx), w2 = fexp2(m2 - mx);
    const float inv = 1.f / (w1 + w2);
    const float a = w1 * inv, b = w2 * inv;
    const short* s1 = po0 + ((size_t)qs * 64 + row) * 128 + dc;
    short*       s2 = y + ((size_t)bh * NN + it * 64 + row) * 128 + dc;
#pragma unroll
    for (int i = 0; i < 32; i += 8) {
        bf16x8 v1 = *(const bf16x8*)(s1 + i);
        bf16x8 v2 = *(const bf16x8*)(s2 + i);
        bf16x8 ov;
#pragma unroll
        for (int k = 0; k < 8; ++k)
            ov[k] = f2bf(a * bf2f(v1[k]) + b * bf2f(v2[k]));
        *(bf16x8*)(s2 + i) = ov;
    }
}

// ---------------------------------------------------------------------------
// Output GEMM: out[2048][1024] = y @ Wo. R19: BK=128 (16 iterations, was 32)
// -- the kernel is barrier-latency bound (20us vs ~8us L2 floor) and grid
// (32,16)=512 is exactly 2/CU, so the 64KB LDS does NOT cut occupancy (the
// m132 mechanism doesn't apply). Two 64-k halves staged per iteration.
// ---------------------------------------------------------------------------
__global__ __launch_bounds__(256) void gemm_out64(
    const short* __restrict__ yb, const short* __restrict__ wot,
    float* __restrict__ out) {
    __shared__ __align__(16) short As[2][2 * 64 * 64];
    __shared__ __align__(16) short Bs[2][2 * 64 * 64];
    const int tid = threadIdx.x;
    const int m0  = blockIdx.x * 64;
    const int n0  = blockIdx.y * 64;
    const int bb  = m0 >> 10;

    int aPre[2], aOff[2]; const short* bP[2];
#pragma unroll
    for (int i = 0; i < 2; ++i) {
        const int c = i * 256 + tid, row = c >> 3;
        const int src = ((c & 7) ^ (row & 7)) << 3;
        aPre[i] = ((m0 & 1023) + row) * 128 + src;
        bP[i] = wot + (size_t)(n0 + row) * 2048 + src;
        aOff[i] = c * 8;
    }

    const int lane = tid & 63, w = tid >> 6;
    const int wr = (w >> 1) * 32, wc = (w & 1) * 32;
    const int fr = lane & 15;
    const int fo = (lane >> 4) << 3;
    const int sw = (fr & 7) << 3;

    f32x4 acc[2][2];
#pragma unroll
    for (int a = 0; a < 2; ++a)
#pragma unroll
        for (int b = 0; b < 2; ++b) acc[a][b] = (f32x4){0.f, 0.f, 0.f, 0.f};

#define OSTAGE(KT, P) do {                                                    \
        _Pragma("unroll")                                                     \
        for (int hf_ = 0; hf_ < 2; ++hf_) {                                   \
            const int k0_ = (KT) * 128 + hf_ * 64;                            \
            const int hh_ = (k0_ >> 6) & 15, im_ = k0_ >> 10;                 \
            const short* ab_ = yb + ((size_t)(bb * 16 + hh_) << 17) + im_ * 64; \
            _Pragma("unroll")                                                 \
            for (int i_ = 0; i_ < 2; ++i_)                                    \
                GLDS16(ab_ + aPre[i_], &As[P][hf_ * 4096 + aOff[i_]]);        \
            _Pragma("unroll")                                                 \
            for (int i_ = 0; i_ < 2; ++i_)                                    \
                GLDS16(bP[i_] + k0_, &Bs[P][hf_ * 4096 + aOff[i_]]);          \
        }                                                                     \
    } while (0)

    OSTAGE(0, 0);
    __syncthreads();

    for (int kt = 0; kt < 16; ++kt) {
        const int p = kt & 1;
        if (kt < 15) OSTAGE(kt + 1, 1 - p);
#pragma unroll
        for (int ks = 0; ks < 128; ks += 32) {
            const int hb = (ks >> 6) * 4096, kk = ks & 63;
            bf16x8 af[2], bf[2];
#pragma unroll
            for (int a = 0; a < 2; ++a)
                af[a] = *(const bf16x8*)&As[p][hb + (wr + a * 16 + fr) * 64 + ((kk + fo) ^ sw)];
#pragma unroll
            for (int b = 0; b < 2; ++b)
                bf[b] = *(const bf16x8*)&Bs[p][hb + (wc + b * 16 + fr) * 64 + ((kk + fo) ^ sw)];
#pragma unroll
            for (int a = 0; a < 2; ++a)
#pragma unroll
                for (int b = 0; b < 2; ++b)
                    acc[a][b] = __builtin_amdgcn_mfma_f32_16x16x32_bf16(
                        af[a], bf[b], acc[a][b], 0, 0, 0);
        }
        if (kt < 15) __syncthreads();
    }
#undef OSTAGE

    const int cq = (lane >> 4) * 4, l15 = lane & 15;
#pragma unroll
    for (int a = 0; a < 2; ++a)
#pragma unroll
        for (int b = 0; b < 2; ++b)
#pragma unroll
            for (int r = 0; r < 4; ++r)
                out[(size_t)(m0 + wr + a * 16 + cq + r) * 1024 +
                    (n0 + wc + b * 16 + l15)] = acc[a][b][r];
}

// ---------------------------------------------------------------------------
extern "C" void kernel_launch(void* const* d_in, const int* in_sizes, int n_in,
                              void* d_out, int out_size, void* d_ws, size_t ws_size,
                              hipStream_t stream) {
    const float* x         = (const float*)d_in[0];
    const float* Wq        = (const float*)d_in[1];
    const float* Wk        = (const float*)d_in[2];
    const float* Wv        = (const float*)d_in[3];
    const float* Wo        = (const float*)d_in[4];
    const float* omega     = (const float*)d_in[5];
    const float* mu_raw    = (const float*)d_in[6];
    const float* sigma_raw = (const float*)d_in[7];
    const float* eta_raw   = (const float*)d_in[8];
    const float* gamma_raw = (const float*)d_in[9];
    const float* tau       = (const float*)d_in[10];
    const float* nu_raw    = (const float*)d_in[11];
    float* out = (float*)d_out;

    short*  qb  = (short*)d_ws;
    short*  kb  = qb + PK;
    short*  vtb = kb + PK;
    float*  qn  = (float*)(vtb + PK);
    float*  kn  = qn + 32768;
    float4* tbl = (float4*)(kn + 32768);
    short*  wot = (short*)(tbl + HH * TBLR);
    short*  wt  = wot + 2097152;
    short*  xb  = wt + 3 * 2097152;
    short*  yb  = wt;                       // alias (wt dead after qkv)
    short*  po0 = wt + 4194304;             // first-half partials (wt tail, 4MB)
    float*  pml = (float*)xb;               // per-row LSE partials (xb dead after qkv)

    prep<<<dim3(32, 32, 5), 256, 0, stream>>>(
        x, Wq, Wk, Wv, Wo, mu_raw, sigma_raw, eta_raw, gamma_raw,
        xb, wt, wot, tbl);
    gemm_qkv_rot2<<<dim3(32, 16, 3), 256, 0, stream>>>(
        xb, wt, omega, qb, kb, vtb, qn, kn);
    attn_mfma<<<dim3(768), 256, 0, stream>>>(
        qb, kb, vtb, qn, kn, tbl, tau, nu_raw, yb, po0, pml);
    attn_merge<<<dim3(256), 256, 0, stream>>>(po0, pml, yb);
    gemm_out64<<<dim3(32, 16), 256, 0, stream>>>(yb, wot, out);
}